// Round 1
// baseline (7260.733 us; speedup 1.0000x reference)
//
#include <hip/hip_runtime.h>

// Problem constants (match reference)
constexpr int N_OP    = 100000;
constexpr int N_M     = 2000;
constexpr int IN_DIM  = 64;
constexpr int OUT_DIM = 128;
constexpr int E_SEQ_N  = 100000;
constexpr int E_OP2M_N = 2000000;

// ---------------- Projection: Y[nrows,128] = X[nrows,64] @ W[64,128] + b ----------------
__global__ __launch_bounds__(256) void proj_kernel(
    const float* __restrict__ X, const float* __restrict__ W,
    const float* __restrict__ b, float* __restrict__ Y, int nrows) {
  __shared__ float Ws[IN_DIM * OUT_DIM];   // 32 KB
  __shared__ float bs[OUT_DIM];
  __shared__ float Xs[16 * IN_DIM];        // 4 KB
  const int t = threadIdx.x;
  for (int i = t; i < IN_DIM * OUT_DIM; i += 256) Ws[i] = W[i];
  if (t < OUT_DIM) bs[t] = b[t];
  const int row0 = blockIdx.x * 16;
  const int nr = min(16, nrows - row0);
  for (int i = t; i < nr * IN_DIM; i += 256) Xs[i] = X[(size_t)row0 * IN_DIM + i];
  __syncthreads();
  const int c = t & 127;
  #pragma unroll
  for (int k = 0; k < 8; ++k) {
    const int o = t + k * 256;       // 0..2047
    const int r = o >> 7;            // 0..15
    if (r >= nr) break;
    float acc = bs[c];
    #pragma unroll
    for (int j = 0; j < IN_DIM; ++j)
      acc += Xs[r * IN_DIM + j] * Ws[j * OUT_DIM + c];
    Y[(size_t)(row0 + r) * OUT_DIM + c] = acc;
  }
}

// ---------------- Degree counting ----------------
__global__ __launch_bounds__(256) void degree_kernel(
    const int* __restrict__ Eseq, const int* __restrict__ Eop2m,
    int* __restrict__ degSeq, int* __restrict__ degOp, int* __restrict__ degM) {
  const int stride = gridDim.x * blockDim.x;
  for (int e = blockIdx.x * blockDim.x + threadIdx.x; e < E_OP2M_N; e += stride) {
    atomicAdd(&degOp[Eop2m[e]], 1);              // src_op side (agg_to_op denominator)
    atomicAdd(&degM[Eop2m[E_OP2M_N + e]], 1);    // dst_m side (agg_to_m denominator)
    if (e < E_SEQ_N)
      atomicAdd(&degSeq[Eseq[E_SEQ_N + e]], 1);  // dst side of seq edges
  }
}

// ---------------- 1/max(deg,1) ----------------
__global__ __launch_bounds__(256) void inv_kernel(
    const int* __restrict__ degSeq, const int* __restrict__ degOp, const int* __restrict__ degM,
    float* __restrict__ invSeq, float* __restrict__ invOp, float* __restrict__ invM) {
  const int stride = gridDim.x * blockDim.x;
  for (int k = blockIdx.x * blockDim.x + threadIdx.x; k < N_OP; k += stride) {
    invSeq[k] = 1.0f / (float)max(degSeq[k], 1);
    invOp[k]  = 1.0f / (float)max(degOp[k], 1);
  }
  for (int k = blockIdx.x * blockDim.x + threadIdx.x; k < N_M; k += stride)
    invM[k] = 1.0f / (float)max(degM[k], 1);
}

// ---------------- init accumulator: d_out = [H_op_proj ; H_m_proj] ----------------
__global__ __launch_bounds__(256) void copy4_kernel(
    const float4* __restrict__ src, float4* __restrict__ dst, int n4) {
  const int stride = gridDim.x * blockDim.x;
  for (int i = blockIdx.x * blockDim.x + threadIdx.x; i < n4; i += stride)
    dst[i] = src[i];
}

// ---------------- seq edges: accOp[dst] += H_op_proj[src] * invSeq[dst] ----------------
__global__ __launch_bounds__(256) void seq_edge_kernel(
    const int* __restrict__ Eseq, const float* __restrict__ HopProj,
    const float* __restrict__ invSeq, float* __restrict__ accOp) {
  const int idx = blockIdx.x * 256 + threadIdx.x;
  const int edge = idx >> 5;
  if (edge >= E_SEQ_N) return;
  const int c0 = (idx & 31) << 2;
  const int src = Eseq[edge];
  const int dst = Eseq[E_SEQ_N + edge];
  const float w = invSeq[dst];
  const float4 v = *reinterpret_cast<const float4*>(HopProj + (size_t)src * OUT_DIM + c0);
  float* p = accOp + (size_t)dst * OUT_DIM + c0;
  atomicAdd(p + 0, v.x * w);
  atomicAdd(p + 1, v.y * w);
  atomicAdd(p + 2, v.z * w);
  atomicAdd(p + 3, v.w * w);
}

// ---------------- op2m edges, both directions ----------------
// accM[m]  += H_op_proj[op] * invM[m]
// accOp[op]+= H_m_proj[m]   * invOp[op]
__global__ __launch_bounds__(256) void op2m_edge_kernel(
    const int* __restrict__ Eop2m, const float* __restrict__ HopProj,
    const float* __restrict__ HmProj, const float* __restrict__ invOp,
    const float* __restrict__ invM, float* __restrict__ accOp, float* __restrict__ accM) {
  const long long idx = (long long)blockIdx.x * 256 + threadIdx.x;
  const int edge = (int)(idx >> 5);
  if (edge >= E_OP2M_N) return;
  const int c0 = ((int)idx & 31) << 2;
  const int op = Eop2m[edge];
  const int m  = Eop2m[E_OP2M_N + edge];
  const float wm  = invM[m];
  const float wop = invOp[op];
  const float4 a = *reinterpret_cast<const float4*>(HopProj + (size_t)op * OUT_DIM + c0);
  const float4 bv = *reinterpret_cast<const float4*>(HmProj + (size_t)m * OUT_DIM + c0);
  float* pm = accM + (size_t)m * OUT_DIM + c0;
  atomicAdd(pm + 0, a.x * wm);
  atomicAdd(pm + 1, a.y * wm);
  atomicAdd(pm + 2, a.z * wm);
  atomicAdd(pm + 3, a.w * wm);
  float* po = accOp + (size_t)op * OUT_DIM + c0;
  atomicAdd(po + 0, bv.x * wop);
  atomicAdd(po + 1, bv.y * wop);
  atomicAdd(po + 2, bv.z * wop);
  atomicAdd(po + 3, bv.w * wop);
}

// ---------------- in-place ReLU ----------------
__global__ __launch_bounds__(256) void relu4_kernel(float4* __restrict__ x, int n4) {
  const int stride = gridDim.x * blockDim.x;
  for (int i = blockIdx.x * blockDim.x + threadIdx.x; i < n4; i += stride) {
    float4 v = x[i];
    v.x = fmaxf(v.x, 0.0f); v.y = fmaxf(v.y, 0.0f);
    v.z = fmaxf(v.z, 0.0f); v.w = fmaxf(v.w, 0.0f);
    x[i] = v;
  }
}

extern "C" void kernel_launch(void* const* d_in, const int* in_sizes, int n_in,
                              void* d_out, int out_size, void* d_ws, size_t ws_size,
                              hipStream_t stream) {
  const float* H_op  = (const float*)d_in[0];
  const float* H_m   = (const float*)d_in[1];
  const int*   E_seq = (const int*)d_in[2];
  const int*   E_op2m= (const int*)d_in[3];
  const float* W_op  = (const float*)d_in[4];
  const float* b_op  = (const float*)d_in[5];
  const float* W_m   = (const float*)d_in[6];
  const float* b_m   = (const float*)d_in[7];
  float* out = (float*)d_out;

  // workspace layout
  float* HopProj = (float*)d_ws;                    // 12,800,000 floats
  float* HmProj  = HopProj + (size_t)N_OP * OUT_DIM; //    256,000 floats (contiguous after)
  float* invSeq  = HopProj + (size_t)(N_OP + N_M) * OUT_DIM; // 100,000
  float* invOp   = invSeq + N_OP;                   // 100,000
  float* invM    = invOp + N_OP;                    // 2,048 padded
  int*   degSeq  = (int*)(invM + 2048);             // 100,000
  int*   degOp   = degSeq + N_OP;                   // 100,000
  int*   degM    = degOp + N_OP;                    // 2,048 padded

  float* accOp = out;                                // [N_OP,128]
  float* accM  = out + (size_t)N_OP * OUT_DIM;       // [N_M,128]

  // 1. projections
  proj_kernel<<<(N_OP + 15) / 16, 256, 0, stream>>>(H_op, W_op, b_op, HopProj, N_OP);
  proj_kernel<<<(N_M + 15) / 16, 256, 0, stream>>>(H_m, W_m, b_m, HmProj, N_M);

  // 2. degrees
  hipMemsetAsync(degSeq, 0, (size_t)(2 * N_OP + 2048) * sizeof(int), stream);
  degree_kernel<<<2048, 256, 0, stream>>>(E_seq, E_op2m, degSeq, degOp, degM);
  inv_kernel<<<512, 256, 0, stream>>>(degSeq, degOp, degM, invSeq, invOp, invM);

  // 3. init accumulators with projections (contiguous: both proj blocks -> whole d_out)
  const int n4 = (N_OP + N_M) * OUT_DIM / 4;  // 3,264,000
  copy4_kernel<<<2048, 256, 0, stream>>>((const float4*)HopProj, (float4*)out, n4);

  // 4. edge scatters
  {
    const long long threads = (long long)E_SEQ_N * 32;
    seq_edge_kernel<<<(int)((threads + 255) / 256), 256, 0, stream>>>(E_seq, HopProj, invSeq, accOp);
  }
  {
    const long long threads = (long long)E_OP2M_N * 32;
    op2m_edge_kernel<<<(int)((threads + 255) / 256), 256, 0, stream>>>(
        E_op2m, HopProj, HmProj, invOp, invM, accOp, accM);
  }

  // 5. ReLU in place
  relu4_kernel<<<2048, 256, 0, stream>>>((float4*)out, n4);
}

// Round 2
// 1003.552 us; speedup vs baseline: 7.2350x; 7.2350x over previous
//
#include <hip/hip_runtime.h>

// Problem constants (match reference)
constexpr int N_OP    = 100000;
constexpr int N_M     = 2000;
constexpr int IN_DIM  = 64;
constexpr int OUT_DIM = 128;
constexpr int E_SEQ_N  = 100000;
constexpr int E_OP2M_N = 2000000;

// Concatenated degree/scan layout: [degOp(100000) | degM(2000,+48 pad) | degSeq(100000) | 1 extra zero]
constexpr int OFF_OP  = 0;
constexpr int OFF_M   = 100000;
constexpr int OFF_SEQ = 102048;
constexpr int SCAN_N  = 202049;          // elements to scan (incl. trailing zero)
constexpr int SEG_PAD = 202752;          // allocated (multiple of 1024-ish, all zeroed)
constexpr int MCHUNKS = 16;

// ---------------- Projection: Y[nrows,128] = X[nrows,64] @ W[64,128] + b ----------------
__global__ __launch_bounds__(256) void proj_kernel(
    const float* __restrict__ X, const float* __restrict__ W,
    const float* __restrict__ b, float* __restrict__ Y, int nrows) {
  __shared__ float Ws[IN_DIM * OUT_DIM];   // 32 KB
  __shared__ float bs[OUT_DIM];
  __shared__ float Xs[16 * IN_DIM];        // 4 KB
  const int t = threadIdx.x;
  for (int i = t; i < IN_DIM * OUT_DIM; i += 256) Ws[i] = W[i];
  if (t < OUT_DIM) bs[t] = b[t];
  const int row0 = blockIdx.x * 16;
  const int nr = min(16, nrows - row0);
  for (int i = t; i < nr * IN_DIM; i += 256) Xs[i] = X[(size_t)row0 * IN_DIM + i];
  __syncthreads();
  const int c = t & 127;
  #pragma unroll
  for (int k = 0; k < 8; ++k) {
    const int o = t + k * 256;
    const int r = o >> 7;
    if (r >= nr) break;
    float acc = bs[c];
    #pragma unroll
    for (int j = 0; j < IN_DIM; ++j)
      acc += Xs[r * IN_DIM + j] * Ws[j * OUT_DIM + c];
    Y[(size_t)(row0 + r) * OUT_DIM + c] = acc;
  }
}

// ---------------- Degree counting into concatenated deg array ----------------
__global__ __launch_bounds__(256) void degree_kernel(
    const int* __restrict__ Eseq, const int* __restrict__ Eop2m, int* __restrict__ deg) {
  const int stride = gridDim.x * blockDim.x;
  for (int e = blockIdx.x * blockDim.x + threadIdx.x; e < E_OP2M_N; e += stride) {
    atomicAdd(&deg[OFF_OP  + Eop2m[e]], 1);             // keyed by src op
    atomicAdd(&deg[OFF_M   + Eop2m[E_OP2M_N + e]], 1);  // keyed by machine
    if (e < E_SEQ_N)
      atomicAdd(&deg[OFF_SEQ + Eseq[E_SEQ_N + e]], 1);  // keyed by seq dst
  }
}

// ---------------- Hierarchical exclusive scan (1024 elems / block) ----------------
__global__ __launch_bounds__(256) void scanA_kernel(
    const int* __restrict__ in, int* __restrict__ out, int* __restrict__ blockSums, int n) {
  __shared__ int s[256];
  const int base = blockIdx.x * 1024 + threadIdx.x * 4;
  int v[4];
  #pragma unroll
  for (int k = 0; k < 4; ++k) v[k] = (base + k < n) ? in[base + k] : 0;
  const int tsum = v[0] + v[1] + v[2] + v[3];
  s[threadIdx.x] = tsum;
  __syncthreads();
  for (int d = 1; d < 256; d <<= 1) {
    const int x = s[threadIdx.x];
    const int y = (threadIdx.x >= d) ? s[threadIdx.x - d] : 0;
    __syncthreads();
    s[threadIdx.x] = x + y;
    __syncthreads();
  }
  int run = s[threadIdx.x] - tsum;   // exclusive offset of this thread
  if (threadIdx.x == 255) blockSums[blockIdx.x] = s[255];
  #pragma unroll
  for (int k = 0; k < 4; ++k) {
    if (base + k < n) out[base + k] = run;
    run += v[k];
  }
}

__global__ __launch_bounds__(256) void scanB_kernel(int* __restrict__ bs, int nb) {
  __shared__ int s[256];
  const int t = threadIdx.x;
  const int v = (t < nb) ? bs[t] : 0;
  s[t] = v;
  __syncthreads();
  for (int d = 1; d < 256; d <<= 1) {
    const int x = s[t];
    const int y = (t >= d) ? s[t - d] : 0;
    __syncthreads();
    s[t] = x + y;
    __syncthreads();
  }
  if (t < nb) bs[t] = s[t] - v;      // exclusive
}

__global__ __launch_bounds__(256) void scanC_kernel(
    int* __restrict__ out, const int* __restrict__ bs, int n) {
  const int base = blockIdx.x * 1024 + threadIdx.x * 4;
  const int add = bs[blockIdx.x];
  #pragma unroll
  for (int k = 0; k < 4; ++k)
    if (base + k < n) out[base + k] += add;
}

// ---------------- CSR fill ----------------
__global__ __launch_bounds__(256) void fill_op2m_kernel(
    const int* __restrict__ E, const int* __restrict__ S, int* __restrict__ cur,
    int* __restrict__ opL, int* __restrict__ mL) {
  const int e = blockIdx.x * 256 + threadIdx.x;
  if (e >= E_OP2M_N) return;
  const int baseM = S[OFF_M];
  const int op = E[e];
  const int m  = E[E_OP2M_N + e];
  opL[S[OFF_OP + op] + atomicAdd(&cur[OFF_OP + op], 1)] = m;
  mL[(S[OFF_M + m] - baseM) + atomicAdd(&cur[OFF_M + m], 1)] = op;
}

__global__ __launch_bounds__(256) void fill_seq_kernel(
    const int* __restrict__ E, const int* __restrict__ S, int* __restrict__ cur,
    int* __restrict__ seqL) {
  const int e = blockIdx.x * 256 + threadIdx.x;
  if (e >= E_SEQ_N) return;
  const int baseS = S[OFF_SEQ];
  const int src = E[e];
  const int dst = E[E_SEQ_N + e];
  seqL[(S[OFF_SEQ + dst] - baseS) + atomicAdd(&cur[OFF_SEQ + dst], 1)] = src;
}

// ---------------- op output: one wave per op node, fully fused ----------------
__global__ __launch_bounds__(256) void op_out_kernel(
    const float* __restrict__ HopProj, const float* __restrict__ HmProj,
    const int* __restrict__ S, const int* __restrict__ opL,
    const int* __restrict__ seqL, float* __restrict__ out) {
  const int wid = (blockIdx.x * 256 + threadIdx.x) >> 6;
  if (wid >= N_OP) return;
  const int lane = threadIdx.x & 63;
  const int i = wid;
  float2 acc = *reinterpret_cast<const float2*>(HopProj + (size_t)i * OUT_DIM + lane * 2);

  // seq aggregation (mean over incoming seq edges)
  const int baseS = S[OFF_SEQ];
  const int s0 = S[OFF_SEQ + i] - baseS;
  const int s1 = S[OFF_SEQ + i + 1] - baseS;
  float2 a = make_float2(0.f, 0.f);
  for (int e = s0; e < s1; ++e) {
    const int src = seqL[e];
    const float2 v = *reinterpret_cast<const float2*>(HopProj + (size_t)src * OUT_DIM + lane * 2);
    a.x += v.x; a.y += v.y;
  }
  const float wS = 1.0f / (float)max(s1 - s0, 1);
  acc.x += a.x * wS; acc.y += a.y * wS;

  // machine aggregation (mean of HmProj over incident op2m edges)
  const int o0 = S[OFF_OP + i];
  const int o1 = S[OFF_OP + i + 1];
  float2 b = make_float2(0.f, 0.f);
  int e = o0;
  for (; e + 2 <= o1; e += 2) {
    const int m0 = opL[e];
    const int m1 = opL[e + 1];
    const float2 v0 = *reinterpret_cast<const float2*>(HmProj + (size_t)m0 * OUT_DIM + lane * 2);
    const float2 v1 = *reinterpret_cast<const float2*>(HmProj + (size_t)m1 * OUT_DIM + lane * 2);
    b.x += v0.x + v1.x; b.y += v0.y + v1.y;
  }
  for (; e < o1; ++e) {
    const int m0 = opL[e];
    const float2 v0 = *reinterpret_cast<const float2*>(HmProj + (size_t)m0 * OUT_DIM + lane * 2);
    b.x += v0.x; b.y += v0.y;
  }
  const float wO = 1.0f / (float)max(o1 - o0, 1);
  acc.x = fmaxf(acc.x + b.x * wO, 0.f);
  acc.y = fmaxf(acc.y + b.y * wO, 0.f);
  *reinterpret_cast<float2*>(out + (size_t)i * OUT_DIM + lane * 2) = acc;
}

// ---------------- machine gather: 2000 machines x MCHUNKS chunks ----------------
__global__ __launch_bounds__(128) void m_gather_kernel(
    const float* __restrict__ HopProj, const int* __restrict__ S,
    const int* __restrict__ mL, float* __restrict__ accMbuf) {
  const int m = blockIdx.x / MCHUNKS;
  const int chunk = blockIdx.x % MCHUNKS;
  const int baseM = S[OFF_M];
  const int s0 = S[OFF_M + m] - baseM;
  const int s1 = S[OFF_M + m + 1] - baseM;
  const int len = s1 - s0;
  const int per = (len + MCHUNKS - 1) / MCHUNKS;
  const int e0 = s0 + chunk * per;
  const int e1 = min(s1, e0 + per);
  if (e0 >= e1) return;
  const int col = threadIdx.x;
  float acc = 0.f;
  int e = e0;
  for (; e + 4 <= e1; e += 4) {
    const int o0 = mL[e], o1 = mL[e + 1], o2 = mL[e + 2], o3 = mL[e + 3];
    const float v0 = HopProj[(size_t)o0 * OUT_DIM + col];
    const float v1 = HopProj[(size_t)o1 * OUT_DIM + col];
    const float v2 = HopProj[(size_t)o2 * OUT_DIM + col];
    const float v3 = HopProj[(size_t)o3 * OUT_DIM + col];
    acc += (v0 + v1) + (v2 + v3);
  }
  for (; e < e1; ++e) acc += HopProj[(size_t)mL[e] * OUT_DIM + col];
  atomicAdd(&accMbuf[m * OUT_DIM + col], acc);
}

// ---------------- machine output ----------------
__global__ __launch_bounds__(256) void m_out_kernel(
    const float* __restrict__ HmProj, const float* __restrict__ accMbuf,
    const int* __restrict__ S, float* __restrict__ outM) {
  const int idx = blockIdx.x * 256 + threadIdx.x;
  if (idx >= N_M * OUT_DIM) return;
  const int m = idx >> 7;
  const int deg = S[OFF_M + m + 1] - S[OFF_M + m];
  const float v = HmProj[idx] + accMbuf[idx] / (float)max(deg, 1);
  outM[idx] = fmaxf(v, 0.f);
}

extern "C" void kernel_launch(void* const* d_in, const int* in_sizes, int n_in,
                              void* d_out, int out_size, void* d_ws, size_t ws_size,
                              hipStream_t stream) {
  const float* H_op   = (const float*)d_in[0];
  const float* H_m    = (const float*)d_in[1];
  const int*   E_seq  = (const int*)d_in[2];
  const int*   E_op2m = (const int*)d_in[3];
  const float* W_op   = (const float*)d_in[4];
  const float* b_op   = (const float*)d_in[5];
  const float* W_m    = (const float*)d_in[6];
  const float* b_m    = (const float*)d_in[7];
  float* out = (float*)d_out;

  // ---- workspace layout (floats/ints are 4B; all offsets in elements) ----
  float* HopProj = (float*)d_ws;                               // 12,800,000
  float* HmProj  = HopProj + (size_t)N_OP * OUT_DIM;           //    256,000
  int*   deg     = (int*)(HmProj + (size_t)N_M * OUT_DIM);     //    202,752 (zeroed)
  int*   cur     = deg + SEG_PAD;                              //    202,752 (zeroed)
  float* accMbuf = (float*)(cur + SEG_PAD);                    //    256,000 (zeroed)
  int*   S       = (int*)(accMbuf + (size_t)N_M * OUT_DIM);    //    202,752
  int*   bsums   = S + SEG_PAD;                                //        512
  int*   opL     = bsums + 512;                                //  2,000,000
  int*   mL      = opL + E_OP2M_N;                             //  2,000,000
  int*   seqL    = mL + E_OP2M_N;                              //    100,000

  // 1. projections
  proj_kernel<<<(N_OP + 15) / 16, 256, 0, stream>>>(H_op, W_op, b_op, HopProj, N_OP);
  proj_kernel<<<(N_M + 15) / 16, 256, 0, stream>>>(H_m, W_m, b_m, HmProj, N_M);

  // 2. zero deg + cur + accMbuf in one contiguous memset
  const size_t zero_bytes = ((size_t)SEG_PAD * 2 + (size_t)N_M * OUT_DIM) * sizeof(int);
  hipMemsetAsync(deg, 0, zero_bytes, stream);

  // 3. degrees
  degree_kernel<<<2048, 256, 0, stream>>>(E_seq, E_op2m, deg);

  // 4. exclusive scan of concatenated degrees -> S
  const int nScanBlocks = (SCAN_N + 1023) / 1024;   // 198
  scanA_kernel<<<nScanBlocks, 256, 0, stream>>>(deg, S, bsums, SCAN_N);
  scanB_kernel<<<1, 256, 0, stream>>>(bsums, nScanBlocks);
  scanC_kernel<<<nScanBlocks, 256, 0, stream>>>(S, bsums, SCAN_N);

  // 5. CSR fills
  fill_op2m_kernel<<<(E_OP2M_N + 255) / 256, 256, 0, stream>>>(E_op2m, S, cur, opL, mL);
  fill_seq_kernel<<<(E_SEQ_N + 255) / 256, 256, 0, stream>>>(E_seq, S, cur, seqL);

  // 6. gather + fuse
  {
    const long long threads = (long long)N_OP * 64;
    op_out_kernel<<<(int)((threads + 255) / 256), 256, 0, stream>>>(
        HopProj, HmProj, S, opL, seqL, out);
  }
  m_gather_kernel<<<N_M * MCHUNKS, 128, 0, stream>>>(HopProj, S, mL, accMbuf);
  m_out_kernel<<<(N_M * OUT_DIM + 255) / 256, 256, 0, stream>>>(
      HmProj, accMbuf, S, out + (size_t)N_OP * OUT_DIM);
}

// Round 3
// 559.532 us; speedup vs baseline: 12.9764x; 1.7936x over previous
//
#include <hip/hip_runtime.h>

// Problem constants (match reference)
constexpr int N_OP    = 100000;
constexpr int N_M     = 2000;
constexpr int IN_DIM  = 64;
constexpr int OUT_DIM = 128;
constexpr int E_SEQ_N  = 100000;
constexpr int E_OP2M_N = 2000000;

// Counting-sort partitioning for the machine axis
constexpr int W_BLK     = 512;                       // partitions of the edge list
constexpr int CHUNK     = (E_OP2M_N + W_BLK - 1) / W_BLK;  // 3907
constexpr int SEQ_CHUNK = (E_SEQ_N + W_BLK - 1) / W_BLK;   // 196

// S layout: scan over [degOp(100000) | degSeq(100000) | trailing 0]
constexpr int OFF_SEQ2 = 100000;
constexpr int SCAN_N2  = 200001;

// ---------------- Projection: Y[nrows,128] = X[nrows,64] @ W[64,128] + b ----------------
__global__ __launch_bounds__(256) void proj_kernel(
    const float* __restrict__ X, const float* __restrict__ W,
    const float* __restrict__ b, float* __restrict__ Y, int nrows) {
  __shared__ float Ws[IN_DIM * OUT_DIM];   // 32 KB
  __shared__ float bs[OUT_DIM];
  __shared__ float Xs[16 * IN_DIM];        // 4 KB
  const int t = threadIdx.x;
  for (int i = t; i < IN_DIM * OUT_DIM; i += 256) Ws[i] = W[i];
  if (t < OUT_DIM) bs[t] = b[t];
  const int row0 = blockIdx.x * 16;
  const int nr = min(16, nrows - row0);
  for (int i = t; i < nr * IN_DIM; i += 256) Xs[i] = X[(size_t)row0 * IN_DIM + i];
  __syncthreads();
  const int c = t & 127;
  #pragma unroll
  for (int k = 0; k < 8; ++k) {
    const int o = t + k * 256;
    const int r = o >> 7;
    if (r >= nr) break;
    float acc = bs[c];
    #pragma unroll
    for (int j = 0; j < IN_DIM; ++j)
      acc += Xs[r * IN_DIM + j] * Ws[j * OUT_DIM + c];
    Y[(size_t)(row0 + r) * OUT_DIM + c] = acc;
  }
}

// ---------------- Phase A: per-block m-histogram + op/seq degree atomics ----------------
__global__ __launch_bounds__(256) void histA_kernel(
    const int* __restrict__ Eseq, const int* __restrict__ Eop2m,
    int* __restrict__ H, int* __restrict__ degOp, int* __restrict__ degSeq) {
  __shared__ int h[N_M];   // 8 KB
  for (int i = threadIdx.x; i < N_M; i += 256) h[i] = 0;
  __syncthreads();
  const int w = blockIdx.x;
  const int e0 = w * CHUNK, e1 = min(E_OP2M_N, e0 + CHUNK);
  for (int e = e0 + threadIdx.x; e < e1; e += 256) {
    atomicAdd(&degOp[Eop2m[e]], 1);
    atomicAdd(&h[Eop2m[E_OP2M_N + e]], 1);
  }
  const int s0 = w * SEQ_CHUNK, s1 = min(E_SEQ_N, s0 + SEQ_CHUNK);
  for (int e = s0 + threadIdx.x; e < s1; e += 256)
    atomicAdd(&degSeq[Eseq[E_SEQ_N + e]], 1);
  __syncthreads();
  for (int i = threadIdx.x; i < N_M; i += 256) H[w * N_M + i] = h[i];
}

// ---------------- Phase B: exclusive column scan of H; degM = column sums ----------------
__global__ __launch_bounds__(512) void colscan_kernel(int* __restrict__ H, int* __restrict__ degM) {
  __shared__ int s[W_BLK];
  const int m = blockIdx.x;
  const int t = threadIdx.x;
  const int v = H[t * N_M + m];
  s[t] = v;
  __syncthreads();
  for (int d = 1; d < W_BLK; d <<= 1) {
    const int x = s[t];
    const int y = (t >= d) ? s[t - d] : 0;
    __syncthreads();
    s[t] = x + y;
    __syncthreads();
  }
  H[t * N_M + m] = s[t] - v;           // exclusive offset of block t within machine m
  if (t == W_BLK - 1) degM[m] = s[W_BLK - 1];
}

// ---------------- baseM: exclusive scan of degM (2000 elems, 1 block) ----------------
__global__ __launch_bounds__(256) void scanM_kernel(
    const int* __restrict__ degM, int* __restrict__ baseM) {
  __shared__ int s[256];
  const int t = threadIdx.x;
  int v[8];
  int sum = 0;
  #pragma unroll
  for (int k = 0; k < 8; ++k) {
    const int i = t * 8 + k;
    v[k] = (i < N_M) ? degM[i] : 0;
    sum += v[k];
  }
  s[t] = sum;
  __syncthreads();
  for (int d = 1; d < 256; d <<= 1) {
    const int x = s[t];
    const int y = (t >= d) ? s[t - d] : 0;
    __syncthreads();
    s[t] = x + y;
    __syncthreads();
  }
  int run = s[t] - sum;
  #pragma unroll
  for (int k = 0; k < 8; ++k) {
    const int i = t * 8 + k;
    if (i < N_M) baseM[i] = run;
    run += v[k];
  }
}

// ---------------- Hierarchical exclusive scan over [degOp|degSeq] ----------------
__global__ __launch_bounds__(256) void scanA_kernel(
    const int* __restrict__ in, int* __restrict__ out, int* __restrict__ blockSums, int n) {
  __shared__ int s[256];
  const int base = blockIdx.x * 1024 + threadIdx.x * 4;
  int v[4];
  #pragma unroll
  for (int k = 0; k < 4; ++k) v[k] = (base + k < n) ? in[base + k] : 0;
  const int tsum = v[0] + v[1] + v[2] + v[3];
  s[threadIdx.x] = tsum;
  __syncthreads();
  for (int d = 1; d < 256; d <<= 1) {
    const int x = s[threadIdx.x];
    const int y = (threadIdx.x >= d) ? s[threadIdx.x - d] : 0;
    __syncthreads();
    s[threadIdx.x] = x + y;
    __syncthreads();
  }
  int run = s[threadIdx.x] - tsum;
  if (threadIdx.x == 255) blockSums[blockIdx.x] = s[255];
  #pragma unroll
  for (int k = 0; k < 4; ++k) {
    if (base + k < n) out[base + k] = run;
    run += v[k];
  }
}

__global__ __launch_bounds__(256) void scanB_kernel(int* __restrict__ bs, int nb) {
  __shared__ int s[256];
  const int t = threadIdx.x;
  const int v = (t < nb) ? bs[t] : 0;
  s[t] = v;
  __syncthreads();
  for (int d = 1; d < 256; d <<= 1) {
    const int x = s[t];
    const int y = (t >= d) ? s[t - d] : 0;
    __syncthreads();
    s[t] = x + y;
    __syncthreads();
  }
  if (t < nb) bs[t] = s[t] - v;
}

__global__ __launch_bounds__(256) void scanC_kernel(
    int* __restrict__ out, const int* __restrict__ bs, int n) {
  const int base = blockIdx.x * 1024 + threadIdx.x * 4;
  const int add = bs[blockIdx.x];
  #pragma unroll
  for (int k = 0; k < 4; ++k)
    if (base + k < n) out[base + k] += add;
}

// ---------------- Fill all three adjacency lists ----------------
// mL via counting-sort offsets (LDS cursors only); opL/seqL via low-contention cursors.
__global__ __launch_bounds__(256) void fill_kernel(
    const int* __restrict__ Eseq, const int* __restrict__ Eop2m,
    const int* __restrict__ S, const int* __restrict__ H, const int* __restrict__ baseM,
    int* __restrict__ curOp, int* __restrict__ curSeq,
    int* __restrict__ opL, int* __restrict__ mL, int* __restrict__ seqL) {
  __shared__ int lcur[N_M];   // 8 KB
  for (int i = threadIdx.x; i < N_M; i += 256) lcur[i] = 0;
  __syncthreads();
  const int w = blockIdx.x;
  const int base = w * N_M;
  const int e0 = w * CHUNK, e1 = min(E_OP2M_N, e0 + CHUNK);
  for (int e = e0 + threadIdx.x; e < e1; e += 256) {
    const int op = Eop2m[e];
    const int m  = Eop2m[E_OP2M_N + e];
    opL[S[op] + atomicAdd(&curOp[op], 1)] = m;
    mL[baseM[m] + H[base + m] + atomicAdd(&lcur[m], 1)] = op;
  }
  const int s0 = w * SEQ_CHUNK, s1 = min(E_SEQ_N, s0 + SEQ_CHUNK);
  for (int e = s0 + threadIdx.x; e < s1; e += 256) {
    const int src = Eseq[e];
    const int dst = Eseq[E_SEQ_N + e];
    // seqL segment base: S[OFF_SEQ2+dst] - S[OFF_SEQ2]; S[OFF_SEQ2] == E_OP2M_N by construction
    seqL[(S[OFF_SEQ2 + dst] - E_OP2M_N) + atomicAdd(&curSeq[dst], 1)] = src;
  }
}

// ---------------- op output: one wave per op node, fully fused ----------------
__global__ __launch_bounds__(256) void op_out_kernel(
    const float* __restrict__ HopProj, const float* __restrict__ HmProj,
    const int* __restrict__ S, const int* __restrict__ opL,
    const int* __restrict__ seqL, float* __restrict__ out) {
  const int wid = (blockIdx.x * 256 + threadIdx.x) >> 6;
  if (wid >= N_OP) return;
  const int lane = threadIdx.x & 63;
  const int i = wid;
  float2 acc = *reinterpret_cast<const float2*>(HopProj + (size_t)i * OUT_DIM + lane * 2);

  // seq aggregation (mean over incoming seq edges)
  const int s0 = S[OFF_SEQ2 + i] - E_OP2M_N;
  const int s1 = S[OFF_SEQ2 + i + 1] - E_OP2M_N;
  float2 a = make_float2(0.f, 0.f);
  for (int e = s0; e < s1; ++e) {
    const int src = seqL[e];
    const float2 v = *reinterpret_cast<const float2*>(HopProj + (size_t)src * OUT_DIM + lane * 2);
    a.x += v.x; a.y += v.y;
  }
  const float wS = 1.0f / (float)max(s1 - s0, 1);
  acc.x += a.x * wS; acc.y += a.y * wS;

  // machine aggregation (mean of HmProj over incident op2m edges)
  const int o0 = S[i];
  const int o1 = S[i + 1];
  float2 b = make_float2(0.f, 0.f);
  int e = o0;
  for (; e + 2 <= o1; e += 2) {
    const int m0 = opL[e];
    const int m1 = opL[e + 1];
    const float2 v0 = *reinterpret_cast<const float2*>(HmProj + (size_t)m0 * OUT_DIM + lane * 2);
    const float2 v1 = *reinterpret_cast<const float2*>(HmProj + (size_t)m1 * OUT_DIM + lane * 2);
    b.x += v0.x + v1.x; b.y += v0.y + v1.y;
  }
  for (; e < o1; ++e) {
    const int m0 = opL[e];
    const float2 v0 = *reinterpret_cast<const float2*>(HmProj + (size_t)m0 * OUT_DIM + lane * 2);
    b.x += v0.x; b.y += v0.y;
  }
  const float wO = 1.0f / (float)max(o1 - o0, 1);
  acc.x = fmaxf(acc.x + b.x * wO, 0.f);
  acc.y = fmaxf(acc.y + b.y * wO, 0.f);
  *reinterpret_cast<float2*>(out + (size_t)i * OUT_DIM + lane * 2) = acc;
}

// ---------------- machine output: one block per machine, fused mean+residual+relu ----------------
__global__ __launch_bounds__(256) void m_out_kernel(
    const float* __restrict__ HopProj, const float* __restrict__ HmProj,
    const int* __restrict__ mL, const int* __restrict__ baseM, const int* __restrict__ degM,
    float* __restrict__ outM) {
  __shared__ float part[128];
  const int m = blockIdx.x;
  const int s0 = baseM[m];
  const int deg = degM[m];
  const int col = threadIdx.x & 127;
  const int half = threadIdx.x >> 7;
  float acc = 0.f;
  int e = half;
  // unroll by 4 (stride 2 per half)
  for (; e + 6 < deg; e += 8) {
    const int o0 = mL[s0 + e];
    const int o1 = mL[s0 + e + 2];
    const int o2 = mL[s0 + e + 4];
    const int o3 = mL[s0 + e + 6];
    acc += HopProj[(size_t)o0 * OUT_DIM + col];
    acc += HopProj[(size_t)o1 * OUT_DIM + col];
    acc += HopProj[(size_t)o2 * OUT_DIM + col];
    acc += HopProj[(size_t)o3 * OUT_DIM + col];
  }
  for (; e < deg; e += 2) acc += HopProj[(size_t)mL[s0 + e] * OUT_DIM + col];
  if (half == 1) part[col] = acc;
  __syncthreads();
  if (half == 0) {
    const float v = HmProj[m * OUT_DIM + col] + (acc + part[col]) / (float)max(deg, 1);
    outM[m * OUT_DIM + col] = fmaxf(v, 0.f);
  }
}

extern "C" void kernel_launch(void* const* d_in, const int* in_sizes, int n_in,
                              void* d_out, int out_size, void* d_ws, size_t ws_size,
                              hipStream_t stream) {
  const float* H_op   = (const float*)d_in[0];
  const float* H_m    = (const float*)d_in[1];
  const int*   E_seq  = (const int*)d_in[2];
  const int*   E_op2m = (const int*)d_in[3];
  const float* W_op   = (const float*)d_in[4];
  const float* b_op   = (const float*)d_in[5];
  const float* W_m    = (const float*)d_in[6];
  const float* b_m    = (const float*)d_in[7];
  float* out = (float*)d_out;

  // ---- workspace layout (element offsets, 4B each) ----
  float* HopProj = (float*)d_ws;                                // 12,800,000
  float* HmProj  = HopProj + (size_t)N_OP * OUT_DIM;            //    256,000
  int*   degOp   = (int*)(HmProj + (size_t)N_M * OUT_DIM);      //    100,000 (zeroed)
  int*   degSeq  = degOp + N_OP;                                //    100,000 (zeroed)
  int*   curOp   = degSeq + N_OP;                               //    100,000 (zeroed)
  int*   curSeq  = curOp + N_OP;                                //    100,000 (zeroed)
  int*   degM    = curSeq + N_OP;                               //      2,048
  int*   baseM   = degM + 2048;                                 //      2,048
  int*   S       = baseM + 2048;                                //    200,704
  int*   bsums   = S + 200704;                                  //        512
  int*   Hh      = bsums + 512;                                 //  1,024,000 (W_BLK * N_M)
  int*   opL     = Hh + (size_t)W_BLK * N_M;                    //  2,000,000
  int*   mL      = opL + E_OP2M_N;                              //  2,000,000
  int*   seqL    = mL + E_OP2M_N;                               //    100,000

  // 1. projections
  proj_kernel<<<(N_OP + 15) / 16, 256, 0, stream>>>(H_op, W_op, b_op, HopProj, N_OP);
  proj_kernel<<<(N_M + 15) / 16, 256, 0, stream>>>(H_m, W_m, b_m, HmProj, N_M);

  // 2. zero degOp/degSeq/curOp/curSeq (contiguous)
  hipMemsetAsync(degOp, 0, (size_t)4 * N_OP * sizeof(int), stream);

  // 3. machine histograms + op/seq degrees
  histA_kernel<<<W_BLK, 256, 0, stream>>>(E_seq, E_op2m, Hh, degOp, degSeq);

  // 4. column scan of H -> per-block offsets + degM; then baseM
  colscan_kernel<<<N_M, W_BLK, 0, stream>>>(Hh, degM);
  scanM_kernel<<<1, 256, 0, stream>>>(degM, baseM);

  // 5. exclusive scan of [degOp|degSeq] -> S
  const int nScanBlocks = (SCAN_N2 + 1023) / 1024;   // 196
  scanA_kernel<<<nScanBlocks, 256, 0, stream>>>(degOp, S, bsums, SCAN_N2);
  scanB_kernel<<<1, 256, 0, stream>>>(bsums, nScanBlocks);
  scanC_kernel<<<nScanBlocks, 256, 0, stream>>>(S, bsums, SCAN_N2);

  // 6. fill adjacency lists
  fill_kernel<<<W_BLK, 256, 0, stream>>>(E_seq, E_op2m, S, Hh, baseM,
                                         curOp, curSeq, opL, mL, seqL);

  // 7. outputs
  {
    const long long threads = (long long)N_OP * 64;
    op_out_kernel<<<(int)((threads + 255) / 256), 256, 0, stream>>>(
        HopProj, HmProj, S, opL, seqL, out);
  }
  m_out_kernel<<<N_M, 256, 0, stream>>>(HopProj, HmProj, mL, baseM, degM,
                                        out + (size_t)N_OP * OUT_DIM);
}